// Round 3
// baseline (209.279 us; speedup 1.0000x reference)
//
#include <hip/hip_runtime.h>
#include <math.h>

#define N_ROWS 131072
#define DIM 1024
#define KNNK 32
#define NW1 128                      // k_sel1 waves (1 per block)
#define ROWS_PER_W (N_ROWS / NW1)    // 1024 rows per sel1 wave
#define CANDS (NW1 * KNNK)           // 4096 candidates per class
#define NW_KL 4096                   // k_kl waves (1024 blocks x 4 waves)

__device__ __forceinline__ float wave_sum(float v) {
#pragma unroll
  for (int off = 32; off > 0; off >>= 1) v += __shfl_xor(v, off, 64);
  return v;
}

// two independent butterfly sums — chains interleave in the pipe
__device__ __forceinline__ void wave_sum2(float& a, float& b) {
#pragma unroll
  for (int off = 32; off > 0; off >>= 1) {
    a += __shfl_xor(a, off, 64);
    b += __shfl_xor(b, off, 64);
  }
}

__device__ __forceinline__ float4 sqdiff(float4 a, float m) {
  float4 r;
  r.x = (a.x - m) * (a.x - m);
  r.y = (a.y - m) * (a.y - m);
  r.z = (a.z - m) * (a.z - m);
  r.w = (a.w - m) * (a.w - m);
  return r;
}

__device__ __forceinline__ float sum4(float4 a) {
  return (a.x + a.y) + (a.z + a.w);
}

__device__ __forceinline__ float acc4(float4 a, float4 m, float mean, float p) {
  float d;
  d = a.x - mean; p += fabsf(d * d - m.x);
  d = a.y - mean; p += fabsf(d * d - m.y);
  d = a.z - mean; p += fabsf(d * d - m.z);
  d = a.w - mean; p += fabsf(d * d - m.w);
  return p;
}

// ---- kernel 1: kl[i] = sum_j |(A[i,j]-mean_i)^2 - (q[j]-mean_q)^2| --------
// Register-double-buffered, 2 rows per step (independent chains interleave),
// prefetch next pair while computing current: loads stay in flight ~100%.
__global__ void __launch_bounds__(256, 4) k_kl(const float* __restrict__ A,
                                               const float* __restrict__ q,
                                               float* __restrict__ kl) {
  int t = threadIdx.x;
  int lane = t & 63;
  int gw = blockIdx.x * 4 + (t >> 6);   // wave id in [0, NW_KL)

  const float4* Q4 = reinterpret_cast<const float4*>(q);
  float4 q0 = Q4[lane], q1 = Q4[64 + lane], q2 = Q4[128 + lane], q3 = Q4[192 + lane];
  float qs = sum4(q0) + sum4(q1) + sum4(q2) + sum4(q3);
  qs = wave_sum(qs);
  float qm = qs * (1.0f / DIM);
  float4 m0 = sqdiff(q0, qm), m1 = sqdiff(q1, qm),
         m2 = sqdiff(q2, qm), m3 = sqdiff(q3, qm);

  const float4* A4 = reinterpret_cast<const float4*>(A);

  float4 aA0, aA1, aA2, aA3, aB0, aB1, aB2, aB3;  // current pair (rows r, r+NW_KL)
  float4 bA0, bA1, bA2, bA3, bB0, bB1, bB2, bB3;  // prefetch pair

#define LDP(RA0, RA1, RA2, RA3, RB0, RB1, RB2, RB3, row)                    \
  do {                                                                      \
    const float4* _p = A4 + (size_t)(row) * 256 + lane;                     \
    const float4* _q = _p + (size_t)NW_KL * 256;                            \
    RA0 = _p[0]; RA1 = _p[64]; RA2 = _p[128]; RA3 = _p[192];                \
    RB0 = _q[0]; RB1 = _q[64]; RB2 = _q[128]; RB3 = _q[192];                \
  } while (0)

#define CMP2(RA0, RA1, RA2, RA3, RB0, RB1, RB2, RB3, row)                   \
  do {                                                                      \
    float sA = sum4(RA0) + sum4(RA1) + sum4(RA2) + sum4(RA3);               \
    float sB = sum4(RB0) + sum4(RB1) + sum4(RB2) + sum4(RB3);               \
    wave_sum2(sA, sB);                                                      \
    float mA = sA * (1.0f / DIM), mB = sB * (1.0f / DIM);                   \
    float pA = 0.0f, pB = 0.0f;                                             \
    pA = acc4(RA0, m0, mA, pA); pB = acc4(RB0, m0, mB, pB);                 \
    pA = acc4(RA1, m1, mA, pA); pB = acc4(RB1, m1, mB, pB);                 \
    pA = acc4(RA2, m2, mA, pA); pB = acc4(RB2, m2, mB, pB);                 \
    pA = acc4(RA3, m3, mA, pA); pB = acc4(RB3, m3, mB, pB);                 \
    wave_sum2(pA, pB);                                                      \
    if (lane == 0) { kl[(row)] = pA; kl[(row) + NW_KL] = pB; }              \
  } while (0)

  int r = gw;
  LDP(aA0, aA1, aA2, aA3, aB0, aB1, aB2, aB3, r);
#pragma unroll 1
  for (int it = 0; it < 8; ++it) {
    LDP(bA0, bA1, bA2, bA3, bB0, bB1, bB2, bB3, r + 2 * NW_KL);
    CMP2(aA0, aA1, aA2, aA3, aB0, aB1, aB2, aB3, r);
    if (it < 7) LDP(aA0, aA1, aA2, aA3, aB0, aB1, aB2, aB3, r + 4 * NW_KL);
    CMP2(bA0, bA1, bA2, bA3, bB0, bB1, bB2, bB3, r + 2 * NW_KL);
    r += 4 * NW_KL;
  }
#undef LDP
#undef CMP2
}

// ---- kernel 2: per-wave per-class 32 smallest (barrier-free) --------------
// grid = NW1 blocks x 64 threads. Wave w owns rows [w*1024, w*1024+1024).
// Outputs sorted-ascending 32 values per class: cand[c*CANDS + w*32 + it].
__global__ void __launch_bounds__(64) k_sel1(const float* __restrict__ kl,
                                             const int* __restrict__ lab,
                                             float* __restrict__ cand) {
  int w = blockIdx.x;
  int lane = threadIdx.x;
  int base = w * ROWS_PER_W;
  float v[16];
  int lb[16];
#pragma unroll
  for (int k = 0; k < 16; ++k) {
    v[k] = kl[base + k * 64 + lane];
    lb[k] = lab[base + k * 64 + lane];
  }
  for (int c = 0; c < 2; ++c) {
    float wv[16];
#pragma unroll
    for (int k = 0; k < 16; ++k) wv[k] = (lb[k] == c) ? v[k] : INFINITY;
    for (int it = 0; it < KNNK; ++it) {
      float mv = wv[0];
      int mi = 0;
#pragma unroll
      for (int k = 1; k < 16; ++k)
        if (wv[k] < mv) { mv = wv[k]; mi = k; }
      int gi = mi * 64 + lane;
#pragma unroll
      for (int off = 32; off > 0; off >>= 1) {
        float ov = __shfl_xor(mv, off, 64);
        int oi = __shfl_xor(gi, off, 64);
        if (ov < mv || (ov == mv && oi < gi)) { mv = ov; gi = oi; }
      }
      if (lane == 0) cand[(c * NW1 + w) * KNNK + it] = mv;
      int kw = gi >> 6, lw = gi & 63;
#pragma unroll
      for (int k = 0; k < 16; ++k)
        wv[k] = (lane == lw && k == kw) ? INFINITY : wv[k];
    }
  }
}

// ---- kernel 3: final select + merge + vote (single block, 512 thr) --------
__global__ void __launch_bounds__(512) k_sel2f(const float* __restrict__ cand,
                                               float* __restrict__ out) {
  int t = threadIdx.x;
  int lane = t & 63, wid = t >> 6;
  int c = wid >> 2, qtr = wid & 3;
  const float* src = cand + c * CANDS + qtr * 1024;

  __shared__ float s1[2][4][KNNK];
  __shared__ float s2[2][KNNK];
  __shared__ float idm[2];

  float wv[16];
#pragma unroll
  for (int k = 0; k < 16; ++k) wv[k] = src[k * 64 + lane];
  for (int it = 0; it < KNNK; ++it) {
    float mv = wv[0];
    int mi = 0;
#pragma unroll
    for (int k = 1; k < 16; ++k)
      if (wv[k] < mv) { mv = wv[k]; mi = k; }
    int gi = mi * 64 + lane;
#pragma unroll
    for (int off = 32; off > 0; off >>= 1) {
      float ov = __shfl_xor(mv, off, 64);
      int oi = __shfl_xor(gi, off, 64);
      if (ov < mv || (ov == mv && oi < gi)) { mv = ov; gi = oi; }
    }
    if (lane == 0) s1[c][qtr][it] = mv;
    int kw = gi >> 6, lw = gi & 63;
#pragma unroll
    for (int k = 0; k < 16; ++k)
      wv[k] = (lane == lw && k == kw) ? INFINITY : wv[k];
  }
  __syncthreads();

  if ((wid & 3) == 0) {  // waves 0 and 4: merge 128 -> 32 for class c
    const float* m = &s1[c][0][0];
    float a0 = m[lane], a1 = m[64 + lane];
    float sum = 0.0f;
    for (int it = 0; it < KNNK; ++it) {
      float mv;
      int mi;
      if (a0 <= a1) { mv = a0; mi = 0; } else { mv = a1; mi = 1; }
      int gi = mi * 64 + lane;
#pragma unroll
      for (int off = 32; off > 0; off >>= 1) {
        float ov = __shfl_xor(mv, off, 64);
        int oi = __shfl_xor(gi, off, 64);
        if (ov < mv || (ov == mv && oi < gi)) { mv = ov; gi = oi; }
      }
      if (lane == 0) s2[c][it] = mv;
      sum += mv;  // all lanes hold the winner after the butterfly
      int kw = gi >> 6, lw = gi & 63;
      a0 = (lane == lw && kw == 0) ? INFINITY : a0;
      a1 = (lane == lw && kw == 1) ? INFINITY : a1;
    }
    if (lane == 0) idm[c] = sum * (1.0f / KNNK);
  }
  __syncthreads();

  if (wid == 0) {
    // merge-path: n = #(class-0 entries among global 32 smallest)
    float av = (lane < KNNK) ? s2[0][lane] : 0.0f;
    float bv = (lane < KNNK) ? s2[1][KNNK - 1 - lane] : 1.0f;
    unsigned long long blt = __ballot(lane < KNNK && av <= bv);
    int n = __popcll(blt);
    if (lane == 0) {
      float id0 = idm[0], id1 = idm[1];
      float denom = fmaxf(fabsf(id0) + fabsf(id1), 1e-12f);
      out[0] = (n >= KNNK / 2) ? 0.0f : 1.0f;  // argmax, first-wins on tie
      out[1] = id0 / denom;
      out[2] = id1 / denom;
    }
  }
}

extern "C" void kernel_launch(void* const* d_in, const int* in_sizes, int n_in,
                              void* d_out, int out_size, void* d_ws, size_t ws_size,
                              hipStream_t stream) {
  const float* query = (const float*)d_in[0];
  const float* anchor = (const float*)d_in[1];
  const int* label = (const int*)d_in[2];
  float* out = (float*)d_out;

  float* ws = (float*)d_ws;
  float* kl = ws;                    // 131072
  float* cand = ws + N_ROWS;         // 2*4096

  k_kl<<<NW_KL / 4, 256, 0, stream>>>(anchor, query, kl);
  k_sel1<<<NW1, 64, 0, stream>>>(kl, label, cand);
  k_sel2f<<<1, 512, 0, stream>>>(cand, out);
}